// Round 6
// baseline (344.756 us; speedup 1.0000x reference)
//
#include <hip/hip_runtime.h>
#include <hip/hip_cooperative_groups.h>
#include <hip/hip_bf16.h>
#include <math.h>

namespace cg = cooperative_groups;

typedef __bf16 bf16_t;
typedef __bf16 bf16x8 __attribute__((ext_vector_type(8)));
typedef float f32x4 __attribute__((ext_vector_type(4)));

constexpr int SS = 4096;
constexpr int DD = 1024;
constexpr int HH = 64;

#if __has_builtin(__builtin_amdgcn_exp2f)
#define EXP2F __builtin_amdgcn_exp2f
#else
#define EXP2F exp2f
#endif

static __device__ __forceinline__ f32x4 mfma16(bf16x8 a, bf16x8 b, f32x4 c) {
  return __builtin_amdgcn_mfma_f32_16x16x32_bf16(a, b, c, 0, 0, 0);
}

// One cooperative kernel; phases separated by grid.sync(). 40 KB LDS union -> 4 WG/CU.
__global__ __launch_bounds__(256, 4) void fused(const float* __restrict__ x,
                                                const float* __restrict__ wq,
                                                const float* __restrict__ wk,
                                                const float* __restrict__ wv,
                                                bf16_t* __restrict__ wt,
                                                bf16_t* __restrict__ qo,
                                                bf16_t* __restrict__ ko,
                                                bf16_t* __restrict__ vto,
                                                float* __restrict__ partO,
                                                float* __restrict__ lb,
                                                float* __restrict__ out) {
  __shared__ __align__(16) char smem[40960];
  cg::grid_group grid = cg::this_grid();
  const int nwg = gridDim.x;
  const int wg = blockIdx.x;
  const int tid = threadIdx.x;
  const int wave = tid >> 6, lane = tid & 63, quad = lane >> 4, ml = lane & 15;

  // ================= Phase A: W -> Wt bf16 (LDS transpose), 48 jobs ================
  {
    float* ls = (float*)smem;  // 64 x 68 f32 = 17.4 KB
    for (int job = wg; job < 48; job += nwg) {
      int sel = job >> 4, kb = job & 15, k0 = kb * 64;
      const float* src = (sel == 0) ? wq : ((sel == 1) ? wk : wv);
      int bn = sel * 64;
#pragma unroll
      for (int i = 0; i < 4; ++i) {
        int e = tid + i * 256;
        int r = e >> 4, c4 = (e & 15) * 4;
        *(float4*)&ls[r * 68 + c4] = *(const float4*)(src + (size_t)(k0 + r) * 64 + c4);
      }
      __syncthreads();
#pragma unroll
      for (int j = 0; j < 2; ++j) {
        int e = tid + j * 256;
        int n = e >> 3, kg = e & 7;
        bf16x8 v;
#pragma unroll
        for (int t = 0; t < 8; ++t) v[t] = (bf16_t)ls[(kg * 8 + t) * 68 + n];
        *(bf16x8*)(wt + (size_t)(bn + n) * 1024 + k0 + kg * 8) = v;
      }
      __syncthreads();
    }
  }
  grid.sync();

  // ================= Phase B: QKV GEMM, M=32 x N=96, 1024 jobs =====================
  {
    bf16_t* xs = (bf16_t*)smem;            // [2][32*64]  8 KB, XOR-swizzled
    bf16_t* wsh = (bf16_t*)(smem + 8192);  // [2][96*64] 24 KB, XOR-swizzled
    int mh = wave >> 1, nh = wave & 1;
    int srow = tid >> 3, scc = tid & 7;

    for (int job = wg; job < 1024; job += nwg) {
      int mblk = job >> 1, nhalf = job & 1;
      int m0 = mblk * 32;
      int nbase = nhalf * 96;

      f32x4 acc[3];
#pragma unroll
      for (int i = 0; i < 3; ++i) acc[i] = (f32x4){0.f, 0.f, 0.f, 0.f};

      float4 xr[2];
      bf16x8 wr[3];

      auto load_g = [&](int k0) {
        const float* p = x + (size_t)(m0 + srow) * DD + k0 + scc * 8;
        xr[0] = *(const float4*)p;
        xr[1] = *(const float4*)(p + 4);
#pragma unroll
        for (int i = 0; i < 3; ++i) {
          int c = tid + i * 256;
          int r = c >> 3, cc = c & 7;
          wr[i] = *(const bf16x8*)(wt + (size_t)(nbase + r) * DD + k0 + cc * 8);
        }
      };
      auto store_lds = [&](int bf) {
        bf16x8 v;
        v[0] = (bf16_t)xr[0].x; v[1] = (bf16_t)xr[0].y;
        v[2] = (bf16_t)xr[0].z; v[3] = (bf16_t)xr[0].w;
        v[4] = (bf16_t)xr[1].x; v[5] = (bf16_t)xr[1].y;
        v[6] = (bf16_t)xr[1].z; v[7] = (bf16_t)xr[1].w;
        *(bf16x8*)&xs[bf * 2048 + srow * 64 + ((scc ^ (srow & 7)) * 8)] = v;
#pragma unroll
        for (int i = 0; i < 3; ++i) {
          int c = tid + i * 256;
          int r = c >> 3, cc = c & 7;
          *(bf16x8*)&wsh[bf * 6144 + r * 64 + ((cc ^ (r & 7)) * 8)] = wr[i];
        }
      };

      load_g(0);
      __syncthreads();  // previous job's LDS reads complete
      store_lds(0);
      load_g(64);
      __syncthreads();
      for (int it = 0; it < 16; ++it) {
        int bf = it & 1;
#pragma unroll
        for (int s = 0; s < 2; ++s) {
          int rchunk = ((s * 4 + quad) ^ (ml & 7)) * 8;
          bf16x8 a = *(const bf16x8*)&xs[bf * 2048 + (mh * 16 + ml) * 64 + rchunk];
#pragma unroll
          for (int i = 0; i < 3; ++i) {
            bf16x8 bfr =
                *(const bf16x8*)&wsh[bf * 6144 + (nh * 48 + i * 16 + ml) * 64 + rchunk];
            acc[i] = mfma16(a, bfr, acc[i]);
          }
        }
        if (it < 15) {
          store_lds(1 - bf);
          if (it < 14) load_g((it + 2) * 64);
          __syncthreads();
        }
      }

      int b = m0 >> 12;
      int sr = m0 & 4095;
      const float QSCALE = 0.18033688011112042f;  // log2(e)/sqrt(64)
      bf16_t* vls = xs;                           // overlay: 64 x 40 = 5 KB
      __syncthreads();                            // xs reads done before overlay
#pragma unroll
      for (int i = 0; i < 3; ++i) {
        int col = nbase + nh * 48 + i * 16 + ml;
#pragma unroll
        for (int r = 0; r < 4; ++r) {
          int lrow = mh * 16 + quad * 4 + r;
          size_t grow = (size_t)b * SS + sr + lrow;
          if (col < 64) qo[grow * HH + col] = (bf16_t)(acc[i][r] * QSCALE);
          else if (col < 128) ko[grow * HH + (col - 64)] = (bf16_t)(acc[i][r]);
          else vls[(col - 128) * 40 + lrow] = (bf16_t)(acc[i][r]);
        }
      }
      __syncthreads();
      if (nhalf == 1) {
        int h = tid >> 2, sg = tid & 3;
        *(bf16x8*)(vto + ((size_t)b * HH + h) * SS + sr + sg * 8) =
            *(const bf16x8*)&vls[h * 40 + sg * 8];
      }
    }
  }
  grid.sync();

  // ================= Phase C: flash attention, 832 jobs ============================
  {
    bf16_t* Kl = (bf16_t*)smem;             // [2][64*64] 16 KB dbuf, swizzled
    bf16_t* Vl = (bf16_t*)(smem + 16384);   // [2][64*64] 16 KB dbuf, swizzled
    bf16_t* Pl = (bf16_t*)(smem + 32768);   // [4][16*64]  8 KB per-wave scratch
    int srl = tid >> 3, scc = tid & 7;

    for (int job = wg; job < 832; job += nwg) {
      int b, jt, c0, len, slot = 0;
      bool direct;
      if (job < 768) {
        jt = 63 - (job >> 4);
        int rem = job & 15;
        b = rem >> 2;
        int ch = rem & 3;
        int L = (jt + 4) >> 2;
        c0 = ch * L;
        int c1 = c0 + L; if (c1 > jt + 1) c1 = jt + 1;
        len = c1 - c0;
        slot = (b * 48 + (jt - 16)) * 4 + ch;
        direct = false;
      } else {
        int idx = job - 768;
        jt = 15 - (idx >> 2);
        b = idx & 3;
        c0 = 0;
        len = jt + 1;
        direct = true;
      }
      int q0 = jt * 64;

      const bf16_t* qb = qo + (size_t)b * SS * HH;
      const bf16_t* kb = ko + (size_t)b * SS * HH;
      const bf16_t* vb = vto + (size_t)b * HH * SS;

      int qrow = q0 + wave * 16 + ml;
      bf16x8 aq0 = *(const bf16x8*)(qb + (size_t)qrow * HH + quad * 8);
      bf16x8 aq1 = *(const bf16x8*)(qb + (size_t)qrow * HH + 32 + quad * 8);

      bf16x8 kreg[2], vreg[2];
      auto load_kv = [&](int kt) {
#pragma unroll
        for (int i = 0; i < 2; ++i) {
          int r = srl + i * 32;
          kreg[i] = *(const bf16x8*)(kb + (size_t)(kt * 64 + r) * HH + scc * 8);
          vreg[i] = *(const bf16x8*)(vb + (size_t)r * SS + kt * 64 + scc * 8);
        }
      };
      auto store_kv = [&](int bf) {
#pragma unroll
        for (int i = 0; i < 2; ++i) {
          int r = srl + i * 32;
          int off = r * 64 + ((scc ^ (r & 7)) * 8);
          *(bf16x8*)&Kl[bf * 4096 + off] = kreg[i];
          *(bf16x8*)&Vl[bf * 4096 + off] = vreg[i];
        }
      };

      f32x4 oa[4];
#pragma unroll
      for (int i = 0; i < 4; ++i) oa[i] = (f32x4){0.f, 0.f, 0.f, 0.f};
      float lr[4] = {0.f, 0.f, 0.f, 0.f};

      load_kv(c0);
      __syncthreads();  // previous job's LDS reads complete
      store_kv(0);

      for (int i = 0; i < len; ++i) {
        int kt = c0 + i;
        int bf = i & 1;
        __syncthreads();                    // buf bf ready
        if (i + 1 < len) load_kv(kt + 1);   // next tile's loads in flight

        f32x4 sa[4];
#pragma unroll
        for (int nt = 0; nt < 4; ++nt) sa[nt] = (f32x4){0.f, 0.f, 0.f, 0.f};
#pragma unroll
        for (int s = 0; s < 2; ++s) {
          bf16x8 a = s ? aq1 : aq0;
          int rchunk = ((s * 4 + quad) ^ (ml & 7)) * 8;
#pragma unroll
          for (int nt = 0; nt < 4; ++nt) {
            bf16x8 bfr = *(const bf16x8*)&Kl[bf * 4096 + (nt * 16 + ml) * 64 + rchunk];
            sa[nt] = mfma16(a, bfr, sa[nt]);
          }
        }

        if (kt == jt) {
#pragma unroll
          for (int nt = 0; nt < 4; ++nt) {
            int key = kt * 64 + nt * 16 + ml;
#pragma unroll
            for (int r = 0; r < 4; ++r) {
              int qr = q0 + wave * 16 + quad * 4 + r;
              if (key > qr) sa[nt][r] = -3.38953139e38f;
            }
          }
        }

        // no-max softmax (log2-domain scores bounded; fp32-safe)
#pragma unroll
        for (int r = 0; r < 4; ++r) {
          float p0 = EXP2F(sa[0][r]);
          float p1 = EXP2F(sa[1][r]);
          float p2 = EXP2F(sa[2][r]);
          float p3 = EXP2F(sa[3][r]);
          sa[0][r] = p0; sa[1][r] = p1; sa[2][r] = p2; sa[3][r] = p3;
          lr[r] += (p0 + p1) + (p2 + p3);
        }

        // P: C-layout -> A-layout via per-wave swizzled LDS (same wave, no barrier)
#pragma unroll
        for (int nt = 0; nt < 4; ++nt) {
#pragma unroll
          for (int r = 0; r < 4; ++r) {
            int row = quad * 4 + r;
            int cc = nt * 2 + (ml >> 3);
            Pl[wave * 1024 + row * 64 + ((cc ^ (row & 7)) * 8) + (ml & 7)] =
                (bf16_t)sa[nt][r];
          }
        }
#pragma unroll
        for (int s = 0; s < 2; ++s) {
          int rchunk = ((s * 4 + quad) ^ (ml & 7)) * 8;
          bf16x8 pa = *(const bf16x8*)&Pl[wave * 1024 + ml * 64 + rchunk];
#pragma unroll
          for (int ht = 0; ht < 4; ++ht) {
            bf16x8 bv = *(const bf16x8*)&Vl[bf * 4096 + (ht * 16 + ml) * 64 + rchunk];
            oa[ht] = mfma16(pa, bv, oa[ht]);
          }
        }

        if (i + 1 < len) store_kv(1 - bf);
      }

#pragma unroll
      for (int r = 0; r < 4; ++r) {
        float t = lr[r];
        t += __shfl_xor(t, 1);
        t += __shfl_xor(t, 2);
        t += __shfl_xor(t, 4);
        t += __shfl_xor(t, 8);
        lr[r] = t;
      }

      if (direct) {
#pragma unroll
        for (int r = 0; r < 4; ++r) {
          float inv = 1.0f / lr[r];
          int row = q0 + wave * 16 + quad * 4 + r;
#pragma unroll
          for (int ht = 0; ht < 4; ++ht)
            out[((size_t)b * SS + row) * HH + ht * 16 + ml] = oa[ht][r] * inv;
        }
      } else {
        float* po = partO + (size_t)slot * 4096;
#pragma unroll
        for (int r = 0; r < 4; ++r) {
          int row = wave * 16 + quad * 4 + r;
#pragma unroll
          for (int ht = 0; ht < 4; ++ht)
            po[row * 64 + ht * 16 + ml] = oa[ht][r];
          if (ml == 0) lb[slot * 64 + row] = lr[r];
        }
      }
    }
  }
  grid.sync();

  // ================= Phase D: combine, 384 jobs ====================================
  {
    for (int job = wg; job < 384; job += nwg) {
      int b = job / 96;
      int rest = job - b * 96;
      int jt = 16 + (rest >> 1), half = rest & 1;
      int base = (b * 48 + (jt - 16)) * 4;
      int lr_ = tid >> 3, cb = tid & 7;
      int row = half * 32 + lr_;

      float l = 0.f;
      float4 o0 = {0.f, 0.f, 0.f, 0.f}, o1 = {0.f, 0.f, 0.f, 0.f};
#pragma unroll
      for (int c = 0; c < 4; ++c) {
        l += lb[(base + c) * 64 + row];
        const float* p = partO + (size_t)(base + c) * 4096 + row * 64 + cb * 8;
        float4 a = *(const float4*)p;
        float4 bq = *(const float4*)(p + 4);
        o0.x += a.x; o0.y += a.y; o0.z += a.z; o0.w += a.w;
        o1.x += bq.x; o1.y += bq.y; o1.z += bq.z; o1.w += bq.w;
      }
      float inv = 1.0f / l;
      float* op = out + (((size_t)b * SS) + jt * 64 + row) * HH + cb * 8;
      o0.x *= inv; o0.y *= inv; o0.z *= inv; o0.w *= inv;
      o1.x *= inv; o1.y *= inv; o1.z *= inv; o1.w *= inv;
      *(float4*)op = o0;
      *(float4*)(op + 4) = o1;
    }
  }
}

// ---------------- host ----------------
extern "C" void kernel_launch(void* const* d_in, const int* in_sizes, int n_in,
                              void* d_out, int out_size, void* d_ws, size_t ws_size,
                              hipStream_t stream) {
  const float* x  = (const float*)d_in[0];
  const float* wq = (const float*)d_in[1];
  const float* wk = (const float*)d_in[2];
  const float* wv = (const float*)d_in[3];
  float* out = (float*)d_out;

  char* wsb = (char*)d_ws;
  bf16_t* wt  = (bf16_t*)wsb;                    // 384 KB
  bf16_t* q   = (bf16_t*)(wsb + 524288);         // 2 MB
  bf16_t* k   = (bf16_t*)(wsb + 2621440);        // 2 MB
  bf16_t* vt  = (bf16_t*)(wsb + 4718592);        // 2 MB
  float*  po  = (float*)(wsb + 6815744);         // 12.6 MB (768 slots x 16 KB)
  float*  lb  = (float*)(wsb + 19398656);        // 196 KB

  int occ = 0;
  hipError_t e = hipOccupancyMaxActiveBlocksPerMultiprocessor(&occ, fused, 256, 0);
  int nblk = (e == hipSuccess && occ > 0) ? occ * 256 : 512;
  if (nblk > 1024) nblk = 1024;

  void* args[] = {(void*)&x,  (void*)&wq, (void*)&wk, (void*)&wv, (void*)&wt,
                  (void*)&q,  (void*)&k,  (void*)&vt, (void*)&po, (void*)&lb,
                  (void*)&out};
  hipLaunchCooperativeKernel(fused, dim3(nblk), dim3(256), args, 0, stream);
}

// Round 7
// 147.829 us; speedup vs baseline: 2.3321x; 2.3321x over previous
//
#include <hip/hip_runtime.h>
#include <hip/hip_bf16.h>
#include <math.h>

typedef __bf16 bf16_t;
typedef __bf16 bf16x8 __attribute__((ext_vector_type(8)));
typedef float f32x4 __attribute__((ext_vector_type(4)));

constexpr int SS = 4096;
constexpr int DD = 1024;
constexpr int HH = 64;

#if __has_builtin(__builtin_amdgcn_exp2f)
#define EXP2F __builtin_amdgcn_exp2f
#else
#define EXP2F exp2f
#endif

static __device__ __forceinline__ f32x4 mfma16(bf16x8 a, bf16x8 b, f32x4 c) {
  return __builtin_amdgcn_mfma_f32_16x16x32_bf16(a, b, c, 0, 0, 0);
}

// ---------------- kernel 0: W -> Wt bf16 (coalesced via LDS transpose) -------------
__global__ __launch_bounds__(256) void prep_w(const float* __restrict__ wq,
                                              const float* __restrict__ wk,
                                              const float* __restrict__ wv,
                                              bf16_t* __restrict__ wt) {
  __shared__ float ls[64 * 68];
  int tid = threadIdx.x;
  int sel = blockIdx.x >> 4, kb = blockIdx.x & 15, k0 = kb * 64;
  const float* src = (sel == 0) ? wq : ((sel == 1) ? wk : wv);
  int bn = sel * 64;
#pragma unroll
  for (int i = 0; i < 4; ++i) {
    int e = tid + i * 256;
    int r = e >> 4, c4 = (e & 15) * 4;
    *(float4*)&ls[r * 68 + c4] = *(const float4*)(src + (size_t)(k0 + r) * 64 + c4);
  }
  __syncthreads();
#pragma unroll
  for (int j = 0; j < 2; ++j) {
    int e = tid + j * 256;
    int n = e >> 3, kg = e & 7;
    bf16x8 v;
#pragma unroll
    for (int t = 0; t < 8; ++t) v[t] = (bf16_t)ls[(kg * 8 + t) * 68 + n];
    *(bf16x8*)(wt + (size_t)(bn + n) * 1024 + k0 + kg * 8) = v;
  }
}

// ---------------- kernel 1: QKV GEMM — M=64 x N=96, 512 WGs, dbuf (R5 config) ------
__global__ __launch_bounds__(256) void gemm_qkv(const float* __restrict__ x,
                                                const bf16_t* __restrict__ wt,
                                                bf16_t* __restrict__ qo,
                                                bf16_t* __restrict__ ko,
                                                bf16_t* __restrict__ vto) {
  __shared__ bf16_t xs[2][64 * 64];   // 16 KB dbuf, XOR-swizzled
  __shared__ bf16_t wsh[2][96 * 64];  // 24 KB dbuf, XOR-swizzled
  int tid = threadIdx.x;
  int wave = tid >> 6, lane = tid & 63, quad = lane >> 4, ml = lane & 15;
  int mblk = blockIdx.x >> 1, nhalf = blockIdx.x & 1;
  int m0 = mblk * 64;
  int nbase = nhalf * 96;

  f32x4 acc[6];
#pragma unroll
  for (int i = 0; i < 6; ++i) acc[i] = (f32x4){0.f, 0.f, 0.f, 0.f};

  int xrow = tid >> 2, xseg = tid & 3;
  float4 xr[4];
  bf16x8 wr[3];

  auto load_g = [&](int k0) {
    const float* p = x + (size_t)(m0 + xrow) * DD + k0 + xseg * 16;
    xr[0] = *(const float4*)p;
    xr[1] = *(const float4*)(p + 4);
    xr[2] = *(const float4*)(p + 8);
    xr[3] = *(const float4*)(p + 12);
#pragma unroll
    for (int i = 0; i < 3; ++i) {
      int c = tid + i * 256;
      int r = c >> 3, cc = c & 7;
      wr[i] = *(const bf16x8*)(wt + (size_t)(nbase + r) * DD + k0 + cc * 8);
    }
  };
  auto store_lds = [&](int bf) {
    bf16x8 v0, v1;
    v0[0] = (bf16_t)xr[0].x; v0[1] = (bf16_t)xr[0].y;
    v0[2] = (bf16_t)xr[0].z; v0[3] = (bf16_t)xr[0].w;
    v0[4] = (bf16_t)xr[1].x; v0[5] = (bf16_t)xr[1].y;
    v0[6] = (bf16_t)xr[1].z; v0[7] = (bf16_t)xr[1].w;
    v1[0] = (bf16_t)xr[2].x; v1[1] = (bf16_t)xr[2].y;
    v1[2] = (bf16_t)xr[2].z; v1[3] = (bf16_t)xr[2].w;
    v1[4] = (bf16_t)xr[3].x; v1[5] = (bf16_t)xr[3].y;
    v1[6] = (bf16_t)xr[3].z; v1[7] = (bf16_t)xr[3].w;
    int cc0 = (2 * xseg) ^ (xrow & 7);
    int cc1 = (2 * xseg + 1) ^ (xrow & 7);
    *(bf16x8*)&xs[bf][xrow * 64 + cc0 * 8] = v0;
    *(bf16x8*)&xs[bf][xrow * 64 + cc1 * 8] = v1;
#pragma unroll
    for (int i = 0; i < 3; ++i) {
      int c = tid + i * 256;
      int r = c >> 3, cc = c & 7;
      *(bf16x8*)&wsh[bf][r * 64 + ((cc ^ (r & 7)) * 8)] = wr[i];
    }
  };

  load_g(0);
  store_lds(0);
  load_g(64);
  __syncthreads();
  for (int it = 0; it < 16; ++it) {
    int bf = it & 1;
#pragma unroll
    for (int s = 0; s < 2; ++s) {
      int rchunk = ((s * 4 + quad) ^ (ml & 7)) * 8;
      bf16x8 a = *(const bf16x8*)&xs[bf][(wave * 16 + ml) * 64 + rchunk];
#pragma unroll
      for (int i = 0; i < 6; ++i) {
        bf16x8 bfr = *(const bf16x8*)&wsh[bf][(i * 16 + ml) * 64 + rchunk];
        acc[i] = mfma16(a, bfr, acc[i]);
      }
    }
    if (it < 15) {
      store_lds(1 - bf);
      if (it < 14) load_g((it + 2) * 64);
      __syncthreads();
    }
  }

  int b = m0 >> 12;
  int sr = m0 & 4095;
  const float QSCALE = 0.18033688011112042f;  // log2(e)/sqrt(64)
  bf16_t* vls = (bf16_t*)wsh;                 // overlay: 64 h x 72 stride = 9 KB
#pragma unroll
  for (int i = 0; i < 6; ++i) {
    int col = nbase + i * 16 + ml;
#pragma unroll
    for (int r = 0; r < 4; ++r) {
      int lrow = wave * 16 + quad * 4 + r;
      size_t grow = (size_t)b * SS + sr + lrow;
      if (col < 64) qo[grow * HH + col] = (bf16_t)(acc[i][r] * QSCALE);
      else if (col < 128) ko[grow * HH + (col - 64)] = (bf16_t)(acc[i][r]);
      else vls[(col - 128) * 72 + lrow] = (bf16_t)(acc[i][r]);
    }
  }
  __syncthreads();
  if (nhalf == 1) {
    int h = tid >> 2, sg = tid & 3;
    *(bf16x8*)(vto + ((size_t)b * HH + h) * SS + sr + sg * 16) =
        *(const bf16x8*)&vls[h * 72 + sg * 16];
    *(bf16x8*)(vto + ((size_t)b * HH + h) * SS + sr + sg * 16 + 8) =
        *(const bf16x8*)&vls[h * 72 + sg * 16 + 8];
  }
}

// ---------------- kernel 2: flash attention, 24 KB LDS (6 WG/CU), nch={1,2,4,8} ----
// grid 1376 = 4b x 344 jobs. j = 343-(bid>>2) longest-first, b = bid&3.
// j<8: jt=j direct. [8,24): jt=8+((j-8)>>1), nch2. [24,88): jt=16+((j-24)>>2), nch4.
// [88,344): jt=32+((j-88)>>3), nch8.
__global__ __launch_bounds__(256) void attn_partial(const bf16_t* __restrict__ qg,
                                                    const bf16_t* __restrict__ kg,
                                                    const bf16_t* __restrict__ vg,
                                                    float* __restrict__ partO,
                                                    float* __restrict__ lb,
                                                    float* __restrict__ out) {
  __shared__ bf16_t Kl[64 * 64];      // 8 KB [key][h] swizzled
  __shared__ bf16_t Vl[64 * 64];      // 8 KB [h][key] swizzled
  __shared__ bf16_t Pl[4][16 * 64];   // 8 KB per-wave scratch
  int tid = threadIdx.x;
  int wave = tid >> 6, lane = tid & 63, quad = lane >> 4, ml = lane & 15;

  int bid = blockIdx.x;
  int b = bid & 3;
  int j = 343 - (bid >> 2);
  int jt, ch, nch;
  if (j < 8)        { jt = j;                   ch = 0;            nch = 1; }
  else if (j < 24)  { jt = 8  + ((j - 8) >> 1); ch = (j - 8) & 1;  nch = 2; }
  else if (j < 88)  { jt = 16 + ((j - 24) >> 2); ch = (j - 24) & 3; nch = 4; }
  else              { jt = 32 + ((j - 88) >> 3); ch = (j - 88) & 7; nch = 8; }
  int L = (jt + nch) / nch;           // ceil((jt+1)/nch)
  int c0 = ch * L;
  int c1 = c0 + L; if (c1 > jt + 1) c1 = jt + 1;
  int len = c1 - c0;
  bool direct = (nch == 1);
  int slot = b * 336 + (j - 8);       // valid only when !direct
  int q0 = jt * 64;

  const bf16_t* qb = qg + (size_t)b * SS * HH;
  const bf16_t* kb = kg + (size_t)b * SS * HH;
  const bf16_t* vb = vg + (size_t)b * HH * SS;

  int qrow = q0 + wave * 16 + ml;
  bf16x8 aq0 = *(const bf16x8*)(qb + (size_t)qrow * HH + quad * 8);
  bf16x8 aq1 = *(const bf16x8*)(qb + (size_t)qrow * HH + 32 + quad * 8);

  bf16x8 kreg[2], vreg[2];
  int srl = tid >> 3, scc = tid & 7;
  auto load_kv = [&](int kt) {
#pragma unroll
    for (int i = 0; i < 2; ++i) {
      int r = srl + i * 32;
      kreg[i] = *(const bf16x8*)(kb + (size_t)(kt * 64 + r) * HH + scc * 8);
      vreg[i] = *(const bf16x8*)(vb + (size_t)r * SS + kt * 64 + scc * 8);
    }
  };
  auto store_kv = [&]() {
#pragma unroll
    for (int i = 0; i < 2; ++i) {
      int r = srl + i * 32;
      int off = r * 64 + ((scc ^ (r & 7)) * 8);
      *(bf16x8*)&Kl[off] = kreg[i];
      *(bf16x8*)&Vl[off] = vreg[i];
    }
  };

  f32x4 oa[4];
#pragma unroll
  for (int i = 0; i < 4; ++i) oa[i] = (f32x4){0.f, 0.f, 0.f, 0.f};
  float lr[4] = {0.f, 0.f, 0.f, 0.f};

  load_kv(c0);

  for (int i = 0; i < len; ++i) {
    int kt = c0 + i;
    __syncthreads();                    // prior iter's reads done
    store_kv();
    __syncthreads();                    // staged tile visible
    if (i + 1 < len) load_kv(kt + 1);   // register prefetch hides global latency

    f32x4 sa[4];
#pragma unroll
    for (int nt = 0; nt < 4; ++nt) sa[nt] = (f32x4){0.f, 0.f, 0.f, 0.f};
#pragma unroll
    for (int s = 0; s < 2; ++s) {
      bf16x8 a = s ? aq1 : aq0;
      int rchunk = ((s * 4 + quad) ^ (ml & 7)) * 8;
#pragma unroll
      for (int nt = 0; nt < 4; ++nt) {
        bf16x8 bfr = *(const bf16x8*)&Kl[(nt * 16 + ml) * 64 + rchunk];
        sa[nt] = mfma16(a, bfr, sa[nt]);
      }
    }

    if (kt == jt) {
#pragma unroll
      for (int nt = 0; nt < 4; ++nt) {
        int key = kt * 64 + nt * 16 + ml;
#pragma unroll
        for (int r = 0; r < 4; ++r) {
          int qr = q0 + wave * 16 + quad * 4 + r;
          if (key > qr) sa[nt][r] = -3.38953139e38f;
        }
      }
    }

    // no-max softmax (log2-domain scores bounded; fp32-safe)
#pragma unroll
    for (int r = 0; r < 4; ++r) {
      float p0 = EXP2F(sa[0][r]);
      float p1 = EXP2F(sa[1][r]);
      float p2 = EXP2F(sa[2][r]);
      float p3 = EXP2F(sa[3][r]);
      sa[0][r] = p0; sa[1][r] = p1; sa[2][r] = p2; sa[3][r] = p3;
      lr[r] += (p0 + p1) + (p2 + p3);
    }

    // P: C-layout -> A-layout via per-wave swizzled LDS (same wave, no barrier)
#pragma unroll
    for (int nt = 0; nt < 4; ++nt) {
#pragma unroll
      for (int r = 0; r < 4; ++r) {
        int row = quad * 4 + r;
        int cc = nt * 2 + (ml >> 3);
        Pl[wave][row * 64 + ((cc ^ (row & 7)) * 8) + (ml & 7)] = (bf16_t)sa[nt][r];
      }
    }
#pragma unroll
    for (int s = 0; s < 2; ++s) {
      int rchunk = ((s * 4 + quad) ^ (ml & 7)) * 8;
      bf16x8 pa = *(const bf16x8*)&Pl[wave][ml * 64 + rchunk];
#pragma unroll
      for (int ht = 0; ht < 4; ++ht) {
        bf16x8 bv = *(const bf16x8*)&Vl[(ht * 16 + ml) * 64 + rchunk];
        oa[ht] = mfma16(pa, bv, oa[ht]);
      }
    }
  }

#pragma unroll
  for (int r = 0; r < 4; ++r) {
    float t = lr[r];
    t += __shfl_xor(t, 1);
    t += __shfl_xor(t, 2);
    t += __shfl_xor(t, 4);
    t += __shfl_xor(t, 8);
    lr[r] = t;
  }

  if (direct) {
#pragma unroll
    for (int r = 0; r < 4; ++r) {
      float inv = 1.0f / lr[r];
      int row = q0 + wave * 16 + quad * 4 + r;
#pragma unroll
      for (int ht = 0; ht < 4; ++ht)
        out[((size_t)b * SS + row) * HH + ht * 16 + ml] = oa[ht][r] * inv;
    }
  } else {
    float* po = partO + (size_t)slot * 4096;
#pragma unroll
    for (int r = 0; r < 4; ++r) {
      int row = wave * 16 + quad * 4 + r;
#pragma unroll
      for (int ht = 0; ht < 4; ++ht)
        po[row * 64 + ht * 16 + ml] = oa[ht][r];
      if (ml == 0) lb[slot * 64 + row] = lr[r];
    }
  }
}

// ---------------- kernel 3: combine (plain sum / sum-l), nch in {2,4,8} ------------
__global__ __launch_bounds__(256) void combine(const float* __restrict__ partO,
                                               const float* __restrict__ lb,
                                               float* __restrict__ out) {
  int bid = blockIdx.x;  // 224 = b(4) x jt(8..63)
  int b = bid / 56;
  int jt = 8 + (bid - b * 56);
  int nch, jbase;
  if (jt < 16)      { nch = 2; jbase = 8 + 2 * (jt - 8); }
  else if (jt < 32) { nch = 4; jbase = 24 + 4 * (jt - 16); }
  else              { nch = 8; jbase = 88 + 8 * (jt - 32); }
  int base = b * 336 + (jbase - 8);
  int tid = threadIdx.x;
  int row = tid >> 2, cb = tid & 3;

  float l = 0.f;
  f32x4 o[4];
#pragma unroll
  for (int jj = 0; jj < 4; ++jj) o[jj] = (f32x4){0.f, 0.f, 0.f, 0.f};
  for (int c = 0; c < nch; ++c) {
    l += lb[(base + c) * 64 + row];
    const f32x4* p = (const f32x4*)(partO + (size_t)(base + c) * 4096 + row * 64 + cb * 16);
#pragma unroll
    for (int jj = 0; jj < 4; ++jj) o[jj] += p[jj];
  }
  float inv = 1.0f / l;
  f32x4* op = (f32x4*)(out + (((size_t)b * SS) + jt * 64 + row) * HH + cb * 16);
#pragma unroll
  for (int jj = 0; jj < 4; ++jj) op[jj] = o[jj] * inv;
}

// ---------------- host ----------------
extern "C" void kernel_launch(void* const* d_in, const int* in_sizes, int n_in,
                              void* d_out, int out_size, void* d_ws, size_t ws_size,
                              hipStream_t stream) {
  const float* x  = (const float*)d_in[0];
  const float* wq = (const float*)d_in[1];
  const float* wk = (const float*)d_in[2];
  const float* wv = (const float*)d_in[3];
  float* out = (float*)d_out;

  char* wsb = (char*)d_ws;
  bf16_t* wt  = (bf16_t*)wsb;                    // 384 KB
  bf16_t* q   = (bf16_t*)(wsb + 524288);         // 2 MB
  bf16_t* k   = (bf16_t*)(wsb + 2621440);        // 2 MB
  bf16_t* vt  = (bf16_t*)(wsb + 4718592);        // 2 MB
  float*  po  = (float*)(wsb + 6815744);         // 21.5 MB (1344 slots x 16 KB)
  float*  lb  = (float*)(wsb + 28835840);        // 344 KB

  prep_w<<<48, 256, 0, stream>>>(wq, wk, wv, wt);
  gemm_qkv<<<512, 256, 0, stream>>>(x, wt, q, k, vt);
  attn_partial<<<1376, 256, 0, stream>>>(q, k, vt, po, lb, out);
  combine<<<224, 256, 0, stream>>>(po, lb, out);
}